// Round 9
// baseline (1580.449 us; speedup 1.0000x reference)
//
#include <hip/hip_runtime.h>
#include <hip/hip_bf16.h>

#define F 128          // feature dim
#define F4 32          // feature dim in 4-element quads
#define SCAN_CHUNK 1024
#define NSH 8          // counter shards (one per XCD)

typedef __attribute__((ext_vector_type(8))) short bf16x8;
typedef __attribute__((ext_vector_type(4))) float f32x4;
typedef __attribute__((ext_vector_type(2))) float f32x2;

static __device__ inline unsigned short f2bf(float f) {
    __hip_bfloat16 b = __float2bfloat16(f);
    return *(unsigned short*)&b;
}

__device__ inline float4 bf4_to_f4(ushort4 q) {
    float4 f;
    f.x = __uint_as_float((unsigned)q.x << 16);
    f.y = __uint_as_float((unsigned)q.y << 16);
    f.z = __uint_as_float((unsigned)q.z << 16);
    f.w = __uint_as_float((unsigned)q.w << 16);
    return f;
}

// decode 4 packed fp8-e4m3 bytes -> 4 floats (HW cvt)
__device__ inline float4 fp8x4_to_f4(int w) {
    f32x2 lo = __builtin_amdgcn_cvt_pk_f32_fp8(w, false);
    f32x2 hi = __builtin_amdgcn_cvt_pk_f32_fp8(w, true);
    float4 f;
    f.x = lo[0]; f.y = lo[1]; f.z = hi[0]; f.w = hi[1];
    return f;
}

// encode 1 float -> fp8-e4m3 byte (HW cvt)
__device__ inline unsigned char f_to_fp8(float a) {
    int p = __builtin_amdgcn_cvt_pk_fp8_f32(a, a, 0, false);
    return (unsigned char)(p & 0xFF);
}

// physical XCD id (HW_REG_XCC_ID=20, offset 0, size 4 -> simm16 = (3<<11)|20).
// Correctness does NOT depend on this value (shard id is stored per edge);
// only atomic L2-locality does.
__device__ inline int xcc_id() {
    return (int)(__builtin_amdgcn_s_getreg((3 << 11) | 20) & (NSH - 1));
}

// ---------- fused sharded histogram + per-edge slot assignment ----------
// scnt = NSH planes of n counters; atomics stay XCD-local.
// posb[i] = (shard << 13) | slot_within_shard   (slot < 8192 guaranteed)
__global__ void k_histpos(const int* __restrict__ dst, int* scnt,
                          unsigned short* __restrict__ posb, int e, int n) {
    int i = blockIdx.x * blockDim.x + threadIdx.x;
    if (i >= e) return;
    int sh = xcc_id();
    int pos = atomicAdd(&scnt[(size_t)sh * n + dst[i]], 1);
    posb[i] = (unsigned short)((sh << 13) | pos);
}

// ---------- shard prefix: scnt planes -> per-node shard bases; cnt; dinv ----------
__global__ void k_offs(int* scnt, int* cnt, float* dinv, int n) {
    int v = blockIdx.x * blockDim.x + threadIdx.x;
    if (v >= n) return;
    int tot = 0;
#pragma unroll
    for (int s = 0; s < NSH; ++s) {
        int c = scnt[(size_t)s * n + v];
        scnt[(size_t)s * n + v] = tot;   // exclusive base of shard s
        tot += c;
    }
    cnt[v] = tot;
    dinv[v] = 1.0f / sqrtf((float)tot + 1.0f);
}

// ---------- exclusive scan of cnt[0..n) -> rowptr[0..n) ----------
__global__ void k_scan1(const int* __restrict__ cnt, int* rowptr, int* bsum, int n) {
    __shared__ int s[SCAN_CHUNK];
    int base = blockIdx.x * SCAN_CHUNK;
    int tid = threadIdx.x;
    for (int t = tid; t < SCAN_CHUNK; t += 256)
        s[t] = (base + t < n) ? cnt[base + t] : 0;
    __syncthreads();
    for (int off = 1; off < SCAN_CHUNK; off <<= 1) {
        int v0 = (tid       >= off) ? s[tid       - off] : 0;
        int v1 = (tid + 256 >= off) ? s[tid + 256 - off] : 0;
        int v2 = (tid + 512 >= off) ? s[tid + 512 - off] : 0;
        int v3 = (tid + 768 >= off) ? s[tid + 768 - off] : 0;
        __syncthreads();
        s[tid      ] += v0;
        s[tid + 256] += v1;
        s[tid + 512] += v2;
        s[tid + 768] += v3;
        __syncthreads();
    }
    for (int t = tid; t < SCAN_CHUNK; t += 256)
        if (base + t < n) rowptr[base + t] = s[t] - cnt[base + t];
    if (tid == 0) bsum[blockIdx.x] = s[SCAN_CHUNK - 1];
}

__global__ void k_scan2(int* bsum, int nb) {
    __shared__ int s[128];
    int tid = threadIdx.x;
    int v = (tid < nb) ? bsum[tid] : 0;
    s[tid] = v;
    __syncthreads();
    for (int off = 1; off < 128; off <<= 1) {
        int u = (tid >= off) ? s[tid - off] : 0;
        __syncthreads();
        s[tid] += u;
        __syncthreads();
    }
    if (tid < nb) bsum[tid] = s[tid] - v;   // exclusive
}

__global__ void k_scan3(int* rowptr, const int* __restrict__ bsum, int n, int e) {
    int base = blockIdx.x * SCAN_CHUNK;
    int add = bsum[blockIdx.x];
    for (int t = threadIdx.x; t < SCAN_CHUNK; t += 256)
        if (base + t < n) rowptr[base + t] += add;
    if (blockIdx.x == 0 && threadIdx.x == 0) rowptr[n] = e;
}

// ---------- atomic-free CSR placement ----------
__global__ void k_place(const int* __restrict__ src, const int* __restrict__ dst,
                        const unsigned short* __restrict__ posb,
                        const int* __restrict__ rowptr, const int* __restrict__ soff,
                        int* __restrict__ col, int e, int n) {
    int i = blockIdx.x * blockDim.x + threadIdx.x;
    if (i >= e) return;
    int d = dst[i];
    int pb = (int)posb[i];
    int sh = pb >> 13;
    int pos = pb & 0x1FFF;
    col[rowptr[d] + soff[(size_t)sh * n + d] + pos] = src[i];
}

// ---------- pack all 3 W (fp32 128x128) into MFMA B-fragment order, bf16 ----------
__global__ void k_packW3(const float* __restrict__ W1, const float* __restrict__ W2,
                         const float* __restrict__ W3, unsigned short* __restrict__ Wp) {
    int gb = blockIdx.x;                        // 0..191
    const float* W = (gb < 64) ? W1 : ((gb < 128) ? W2 : W3);
    unsigned short* out = Wp + (size_t)(gb >> 6) * 16384;
    int idx = (gb & 63) * 256 + threadIdx.x;    // 0..16383
    int i    = idx & 7;
    int lane = (idx >> 3) & 63;
    int kk   = (idx >> 9) & 3;
    int ct   = idx >> 11;
    int k = kk * 32 + ((lane >> 4) * 8) + i;
    int c = ct * 16 + (lane & 15);
    out[idx] = f2bf(W[k * F + c]);
}

// ---------- MFMA matmul core (A frags supplied by caller-specific loader) ----------
#define MM_BODY(LOAD_A)                                                            \
    int wave = threadIdx.x >> 6;                                                   \
    int lane = threadIdx.x & 63;                                                   \
    int row0 = blockIdx.x * 64 + wave * 16;                                        \
    if (row0 >= n) return;                                                         \
    f32x4 acc[8];                                                                  \
    _Pragma("unroll")                                                              \
    for (int ct = 0; ct < 8; ++ct) acc[ct] = (f32x4){0.f, 0.f, 0.f, 0.f};          \
    _Pragma("unroll")                                                              \
    for (int kk = 0; kk < 4; ++kk) {                                               \
        bf16x8 a = LOAD_A(kk);                                                     \
        _Pragma("unroll")                                                          \
        for (int ct = 0; ct < 8; ++ct) {                                           \
            bf16x8 b = *(const bf16x8*)(Wp + (((size_t)(ct * 4 + kk) * 64 + lane) * 8)); \
            acc[ct] = __builtin_amdgcn_mfma_f32_16x16x32_bf16(a, b, acc[ct], 0, 0, 0);   \
        }                                                                          \
    }                                                                              \
    int orow0 = row0 + ((lane >> 4) * 4);                                          \
    int col = lane & 15;                                                           \
    _Pragma("unroll")                                                              \
    for (int ct = 0; ct < 8; ++ct) {                                               \
        _Pragma("unroll")                                                          \
        for (int r = 0; r < 4; ++r) {                                              \
            int row = orow0 + r;                                                   \
            if (row < n)                                                           \
                H[(size_t)row * F + ct * 16 + col] = f_to_fp8(acc[ct][r]);         \
        }                                                                          \
    }

// bf16-input variant
__global__ __launch_bounds__(256, 2)
void k_mm(const unsigned short* __restrict__ X,
          const unsigned short* __restrict__ Wp,
          unsigned char* __restrict__ H, int n) {
    const unsigned short* Abase_;
#define LOADA_BF16(kk) (*(const bf16x8*)(Abase_ + (kk) * 32))
    {
        int lane_ = threadIdx.x & 63;
        int row0_ = blockIdx.x * 64 + (threadIdx.x >> 6) * 16;
        int arow_ = row0_ + (lane_ & 15);
        if (arow_ >= n) arow_ = n - 1;
        Abase_ = X + (size_t)arow_ * F + ((lane_ >> 4) * 8);
    }
    MM_BODY(LOADA_BF16)
#undef LOADA_BF16
}

// fp32-input variant (layer 1): converts x to bf16 fragments in-register
__global__ __launch_bounds__(256, 2)
void k_mm_f32(const float* __restrict__ Xf,
              const unsigned short* __restrict__ Wp,
              unsigned char* __restrict__ H, int n) {
    const float* Abasef_;
    {
        int lane_ = threadIdx.x & 63;
        int row0_ = blockIdx.x * 64 + (threadIdx.x >> 6) * 16;
        int arow_ = row0_ + (lane_ & 15);
        if (arow_ >= n) arow_ = n - 1;
        Abasef_ = Xf + (size_t)arow_ * F + ((lane_ >> 4) * 8);
    }
#define LOADA_F32(kk) ({                                            \
        float4 a0 = *(const float4*)(Abasef_ + (kk) * 32);          \
        float4 a1 = *(const float4*)(Abasef_ + (kk) * 32 + 4);      \
        bf16x8 av;                                                  \
        av[0] = (short)f2bf(a0.x); av[1] = (short)f2bf(a0.y);       \
        av[2] = (short)f2bf(a0.z); av[3] = (short)f2bf(a0.w);       \
        av[4] = (short)f2bf(a1.x); av[5] = (short)f2bf(a1.y);       \
        av[6] = (short)f2bf(a1.z); av[7] = (short)f2bf(a1.w);       \
        av; })
    MM_BODY(LOADA_F32)
#undef LOADA_F32
}

// ---------- shared aggregate body: acc = relu(selfloop + gather + bias) ----------
#define AGG_BODY                                                                     \
    float dv = dinv[v];                                                              \
    float4 acc = fp8x4_to_f4(H8[(size_t)v * F4 + lane]);                             \
    float sl = dv * dv;                                                              \
    acc.x *= sl; acc.y *= sl; acc.z *= sl; acc.w *= sl;                              \
    int beg = rowptr[v], end = rowptr[v + 1];                                        \
    int j = beg;                                                                     \
    for (; j + 3 < end; j += 4) {                                                    \
        int s0 = col[j], s1 = col[j + 1], s2 = col[j + 2], s3 = col[j + 3];          \
        float w0 = dinv[s0] * dv, w1 = dinv[s1] * dv;                                \
        float w2 = dinv[s2] * dv, w3 = dinv[s3] * dv;                                \
        int q0 = H8[(size_t)s0 * F4 + lane];                                         \
        int q1 = H8[(size_t)s1 * F4 + lane];                                         \
        int q2 = H8[(size_t)s2 * F4 + lane];                                         \
        int q3 = H8[(size_t)s3 * F4 + lane];                                         \
        float4 h0 = fp8x4_to_f4(q0);                                                 \
        float4 h1 = fp8x4_to_f4(q1);                                                 \
        float4 h2 = fp8x4_to_f4(q2);                                                 \
        float4 h3 = fp8x4_to_f4(q3);                                                 \
        acc.x = fmaf(h0.x, w0, acc.x); acc.y = fmaf(h0.y, w0, acc.y);                \
        acc.z = fmaf(h0.z, w0, acc.z); acc.w = fmaf(h0.w, w0, acc.w);                \
        acc.x = fmaf(h1.x, w1, acc.x); acc.y = fmaf(h1.y, w1, acc.y);                \
        acc.z = fmaf(h1.z, w1, acc.z); acc.w = fmaf(h1.w, w1, acc.w);                \
        acc.x = fmaf(h2.x, w2, acc.x); acc.y = fmaf(h2.y, w2, acc.y);                \
        acc.z = fmaf(h2.z, w2, acc.z); acc.w = fmaf(h2.w, w2, acc.w);                \
        acc.x = fmaf(h3.x, w3, acc.x); acc.y = fmaf(h3.y, w3, acc.y);                \
        acc.z = fmaf(h3.z, w3, acc.z); acc.w = fmaf(h3.w, w3, acc.w);                \
    }                                                                                \
    for (; j < end; ++j) {                                                           \
        int s0 = col[j];                                                             \
        float w0 = dinv[s0] * dv;                                                    \
        float4 h0 = fp8x4_to_f4(H8[(size_t)s0 * F4 + lane]);                         \
        acc.x = fmaf(h0.x, w0, acc.x); acc.y = fmaf(h0.y, w0, acc.y);                \
        acc.z = fmaf(h0.z, w0, acc.z); acc.w = fmaf(h0.w, w0, acc.w);                \
    }                                                                                \
    float4 bb = b4[lane];                                                            \
    acc.x = fmaxf(acc.x + bb.x, 0.f);                                                \
    acc.y = fmaxf(acc.y + bb.y, 0.f);                                                \
    acc.z = fmaxf(acc.z + bb.z, 0.f);                                                \
    acc.w = fmaxf(acc.w + bb.w, 0.f);

// layers 1-2: write bf16 activations
__global__ void k_aggregate(const int* __restrict__ H8,
                            const int* __restrict__ rowptr,
                            const int* __restrict__ col,
                            const float* __restrict__ dinv,
                            const float4* __restrict__ b4,
                            ushort4* __restrict__ outq, int n) {
    int v = blockIdx.x * 8 + (threadIdx.x >> 5);
    int lane = threadIdx.x & 31;
    if (v >= n) return;
    AGG_BODY
    ushort4 o;
    o.x = f2bf(acc.x); o.y = f2bf(acc.y); o.z = f2bf(acc.z); o.w = f2bf(acc.w);
    outq[(size_t)v * F4 + lane] = o;
}

// layer 3: no activation write; reduce straight into pooled[128]
__global__ void k_aggregate_pool(const int* __restrict__ H8,
                                 const int* __restrict__ rowptr,
                                 const int* __restrict__ col,
                                 const float* __restrict__ dinv,
                                 const float4* __restrict__ b4,
                                 float* __restrict__ pooled, int n, float inv_n) {
    int v = blockIdx.x * 8 + (threadIdx.x >> 5);
    int lane = threadIdx.x & 31;
    float4 res = {0.f, 0.f, 0.f, 0.f};
    if (v < n) {
        AGG_BODY
        res = acc;
    }
    __shared__ float4 sm[256];
    sm[threadIdx.x] = res;
    __syncthreads();
    if (threadIdx.x < 32) {
        float4 a = sm[threadIdx.x];
        for (int g = 1; g < 8; ++g) {
            float4 o = sm[g * 32 + threadIdx.x];
            a.x += o.x; a.y += o.y; a.z += o.z; a.w += o.w;
        }
        atomicAdd(&pooled[lane * 4 + 0], a.x * inv_n);
        atomicAdd(&pooled[lane * 4 + 1], a.y * inv_n);
        atomicAdd(&pooled[lane * 4 + 2], a.z * inv_n);
        atomicAdd(&pooled[lane * 4 + 3], a.w * inv_n);
    }
}

// ---------- final FC ----------
__global__ void k_fc(const float* __restrict__ pooled, const float* __restrict__ fcw,
                     const float* __restrict__ fcb, float* out) {
    __shared__ float sm[2 * F];
    int f = threadIdx.x;
    float p = pooled[f];
    sm[f]     = p * fcw[f * 2 + 0];
    sm[f + F] = p * fcw[f * 2 + 1];
    __syncthreads();
    for (int off = 64; off > 0; off >>= 1) {
        if (f < off) {
            sm[f]     += sm[f + off];
            sm[F + f] += sm[F + f + off];
        }
        __syncthreads();
    }
    if (f == 0) {
        out[0] = sm[0] + fcb[0];
        out[1] = sm[F] + fcb[1];
    }
}

extern "C" void kernel_launch(void* const* d_in, const int* in_sizes, int n_in,
                              void* d_out, int out_size, void* d_ws, size_t ws_size,
                              hipStream_t stream) {
    const float* x   = (const float*)d_in[0];
    const int*   ei  = (const int*)  d_in[1];
    const float* W1  = (const float*)d_in[2];
    const float* b1  = (const float*)d_in[3];
    const float* W2  = (const float*)d_in[4];
    const float* b2  = (const float*)d_in[5];
    const float* W3  = (const float*)d_in[6];
    const float* b3  = (const float*)d_in[7];
    const float* fcw = (const float*)d_in[8];
    const float* fcb = (const float*)d_in[9];
    float* out = (float*)d_out;

    const int n = in_sizes[0] / F;     // 100000
    const int e = in_sizes[1] / 2;     // 1600000
    const int* src = ei;
    const int* dst = ei + e;

    // workspace layout (16B-aligned chunks)
    float* ws     = (float*)d_ws;
    float* dinv   = ws;                          // n
    float* pooled = dinv + n;                    // 128
    int*   rowptr = (int*)(pooled + 128);        // n+4
    int*   cnt    = rowptr + (n + 4);            // n
    int*   bsum   = cnt + n;                     // 2048
    int*   scnt   = bsum + 2048;                 // NSH*n (shard counters / bases)
    int*   col    = scnt + (size_t)NSH * n;      // e
    unsigned short* posb = (unsigned short*)(col + e);  // e ushort
    unsigned short* Wp  = posb + ((e + 7) & ~7);        // 3*16384
    unsigned short* Ab  = Wp + 3 * 16384;               // n*F bf16
    unsigned short* Bb  = Ab + (size_t)n * F;           // n*F bf16
    unsigned char*  H8  = (unsigned char*)(Bb + (size_t)n * F);   // n*F fp8

    const int BT = 256;
    dim3 blk(BT);
    int gN    = (n + BT - 1) / BT;
    int gE    = (e + BT - 1) / BT;
    int gAgg  = (n + 7) / 8;
    int gMM   = (n + 63) / 64;
    int nbScan = (n + SCAN_CHUNK - 1) / SCAN_CHUNK;   // 98

    // ---- CSR build: XCD-sharded hist+pos, shard prefix, scan, atomic-free place ----
    hipMemsetAsync(scnt, 0, (size_t)NSH * n * sizeof(int), stream);
    hipMemsetAsync(pooled, 0, F * sizeof(float), stream);
    k_histpos<<<gE, blk, 0, stream>>>(dst, scnt, posb, e, n);
    k_offs   <<<gN, blk, 0, stream>>>(scnt, cnt, dinv, n);
    k_scan1  <<<nbScan, blk, 0, stream>>>(cnt, rowptr, bsum, n);
    k_scan2  <<<1, dim3(128), 0, stream>>>(bsum, nbScan);
    k_scan3  <<<nbScan, blk, 0, stream>>>(rowptr, bsum, n, e);
    k_place  <<<gE, blk, 0, stream>>>(src, dst, posb, rowptr, scnt, col, e, n);

    // ---- weight packing (all 3 layers, one dispatch) ----
    k_packW3<<<192, blk, 0, stream>>>(W1, W2, W3, Wp);

    // ---- 3 GCN layers: X @ W -> fp8 H -> gather(fp32 acc) -> bf16 ----
    // layer 1 (fp32 input, no cvt pass)
    k_mm_f32<<<gMM, blk, 0, stream>>>(x, Wp, H8, n);
    k_aggregate<<<gAgg, blk, 0, stream>>>((const int*)H8, rowptr, col, dinv,
                                          (const float4*)b1, (ushort4*)Ab, n);
    // layer 2
    k_mm<<<gMM, blk, 0, stream>>>(Ab, Wp + 16384, H8, n);
    k_aggregate<<<gAgg, blk, 0, stream>>>((const int*)H8, rowptr, col, dinv,
                                          (const float4*)b2, (ushort4*)Bb, n);
    // layer 3 (aggregate fused with mean-pool; no activation write)
    k_mm<<<gMM, blk, 0, stream>>>(Bb, Wp + 2 * 16384, H8, n);
    k_aggregate_pool<<<gAgg, blk, 0, stream>>>((const int*)H8, rowptr, col, dinv,
                                               (const float4*)b3, pooled, n,
                                               1.0f / (float)n);

    // ---- FC ----
    k_fc<<<1, dim3(F), 0, stream>>>(pooled, fcw, fcb, out);
}

// Round 10
// 442.032 us; speedup vs baseline: 3.5754x; 3.5754x over previous
//
#include <hip/hip_runtime.h>
#include <hip/hip_bf16.h>

#define F 128          // feature dim
#define F4 32          // feature dim in 4-element quads
#define SCAN_CHUNK 1024
#define NSH 8          // counter shards (one per XCD)

typedef __attribute__((ext_vector_type(8))) short bf16x8;
typedef __attribute__((ext_vector_type(4))) float f32x4;
typedef __attribute__((ext_vector_type(2))) float f32x2;

static __device__ inline unsigned short f2bf(float f) {
    __hip_bfloat16 b = __float2bfloat16(f);
    return *(unsigned short*)&b;
}

__device__ inline float4 bf4_to_f4(ushort4 q) {
    float4 f;
    f.x = __uint_as_float((unsigned)q.x << 16);
    f.y = __uint_as_float((unsigned)q.y << 16);
    f.z = __uint_as_float((unsigned)q.z << 16);
    f.w = __uint_as_float((unsigned)q.w << 16);
    return f;
}

// decode 4 packed fp8-e4m3 bytes -> 4 floats (HW cvt)
__device__ inline float4 fp8x4_to_f4(int w) {
    f32x2 lo = __builtin_amdgcn_cvt_pk_f32_fp8(w, false);
    f32x2 hi = __builtin_amdgcn_cvt_pk_f32_fp8(w, true);
    float4 f;
    f.x = lo[0]; f.y = lo[1]; f.z = hi[0]; f.w = hi[1];
    return f;
}

// encode 1 float -> fp8-e4m3 byte (HW cvt)
__device__ inline unsigned char f_to_fp8(float a) {
    int p = __builtin_amdgcn_cvt_pk_fp8_f32(a, a, 0, false);
    return (unsigned char)(p & 0xFF);
}

// physical XCD id; correctness does NOT depend on the value (shard id is
// stored per edge) — only atomic L2-locality does.
__device__ inline int xcc_id() {
    return (int)(__builtin_amdgcn_s_getreg((3 << 11) | 20) & (NSH - 1));
}

// ---------- fused sharded histogram + per-edge slot assignment ----------
__global__ void k_histpos(const int* __restrict__ dst, int* scnt,
                          unsigned short* __restrict__ posb, int e, int n) {
    int i = blockIdx.x * blockDim.x + threadIdx.x;
    if (i >= e) return;
    int sh = xcc_id();
    int pos = atomicAdd(&scnt[(size_t)sh * n + dst[i]], 1);
    posb[i] = (unsigned short)((sh << 13) | pos);
}

// ---------- shard prefix: scnt planes -> per-node shard bases; cnt; dinv ----------
__global__ void k_offs(int* scnt, int* cnt, float* dinv, int n) {
    int v = blockIdx.x * blockDim.x + threadIdx.x;
    if (v >= n) return;
    int tot = 0;
#pragma unroll
    for (int s = 0; s < NSH; ++s) {
        int c = scnt[(size_t)s * n + v];
        scnt[(size_t)s * n + v] = tot;   // exclusive base of shard s
        tot += c;
    }
    cnt[v] = tot;
    dinv[v] = 1.0f / sqrtf((float)tot + 1.0f);
}

// ---------- exclusive scan of cnt[0..n) -> rowptr[0..n) ----------
__global__ void k_scan1(const int* __restrict__ cnt, int* rowptr, int* bsum, int n) {
    __shared__ int s[SCAN_CHUNK];
    int base = blockIdx.x * SCAN_CHUNK;
    int tid = threadIdx.x;
    for (int t = tid; t < SCAN_CHUNK; t += 256)
        s[t] = (base + t < n) ? cnt[base + t] : 0;
    __syncthreads();
    for (int off = 1; off < SCAN_CHUNK; off <<= 1) {
        int v0 = (tid       >= off) ? s[tid       - off] : 0;
        int v1 = (tid + 256 >= off) ? s[tid + 256 - off] : 0;
        int v2 = (tid + 512 >= off) ? s[tid + 512 - off] : 0;
        int v3 = (tid + 768 >= off) ? s[tid + 768 - off] : 0;
        __syncthreads();
        s[tid      ] += v0;
        s[tid + 256] += v1;
        s[tid + 512] += v2;
        s[tid + 768] += v3;
        __syncthreads();
    }
    for (int t = tid; t < SCAN_CHUNK; t += 256)
        if (base + t < n) rowptr[base + t] = s[t] - cnt[base + t];
    if (tid == 0) bsum[blockIdx.x] = s[SCAN_CHUNK - 1];
}

__global__ void k_scan2(int* bsum, int nb) {
    __shared__ int s[128];
    int tid = threadIdx.x;
    int v = (tid < nb) ? bsum[tid] : 0;
    s[tid] = v;
    __syncthreads();
    for (int off = 1; off < 128; off <<= 1) {
        int u = (tid >= off) ? s[tid - off] : 0;
        __syncthreads();
        s[tid] += u;
        __syncthreads();
    }
    if (tid < nb) bsum[tid] = s[tid] - v;   // exclusive
}

__global__ void k_scan3(int* rowptr, const int* __restrict__ bsum, int n, int e) {
    int base = blockIdx.x * SCAN_CHUNK;
    int add = bsum[blockIdx.x];
    for (int t = threadIdx.x; t < SCAN_CHUNK; t += 256)
        if (base + t < n) rowptr[base + t] += add;
    if (blockIdx.x == 0 && threadIdx.x == 0) rowptr[n] = e;
}

// ---------- atomic-free CSR placement ----------
__global__ void k_place(const int* __restrict__ src, const int* __restrict__ dst,
                        const unsigned short* __restrict__ posb,
                        const int* __restrict__ rowptr, const int* __restrict__ soff,
                        int* __restrict__ col, int e, int n) {
    int i = blockIdx.x * blockDim.x + threadIdx.x;
    if (i >= e) return;
    int d = dst[i];
    int pb = (int)posb[i];
    int sh = pb >> 13;
    int pos = pb & 0x1FFF;
    col[rowptr[d] + soff[(size_t)sh * n + d] + pos] = src[i];
}

// ---------- pack all 3 W (fp32 128x128) into MFMA B-fragment order, bf16 ----------
__global__ void k_packW3(const float* __restrict__ W1, const float* __restrict__ W2,
                         const float* __restrict__ W3, unsigned short* __restrict__ Wp) {
    int gb = blockIdx.x;                        // 0..191
    const float* W = (gb < 64) ? W1 : ((gb < 128) ? W2 : W3);
    unsigned short* out = Wp + (size_t)(gb >> 6) * 16384;
    int idx = (gb & 63) * 256 + threadIdx.x;    // 0..16383
    int i    = idx & 7;
    int lane = (idx >> 3) & 63;
    int kk   = (idx >> 9) & 3;
    int ct   = idx >> 11;
    int k = kk * 32 + ((lane >> 4) * 8) + i;
    int c = ct * 16 + (lane & 15);
    out[idx] = f2bf(W[k * F + c]);
}

// ---------- MFMA matmul core (A frags supplied by caller-specific loader) ----------
#define MM_BODY(LOAD_A)                                                            \
    int wave = threadIdx.x >> 6;                                                   \
    int lane = threadIdx.x & 63;                                                   \
    int row0 = blockIdx.x * 64 + wave * 16;                                        \
    if (row0 >= n) return;                                                         \
    f32x4 acc[8];                                                                  \
    _Pragma("unroll")                                                              \
    for (int ct = 0; ct < 8; ++ct) acc[ct] = (f32x4){0.f, 0.f, 0.f, 0.f};          \
    _Pragma("unroll")                                                              \
    for (int kk = 0; kk < 4; ++kk) {                                               \
        bf16x8 a = LOAD_A(kk);                                                     \
        _Pragma("unroll")                                                          \
        for (int ct = 0; ct < 8; ++ct) {                                           \
            bf16x8 b = *(const bf16x8*)(Wp + (((size_t)(ct * 4 + kk) * 64 + lane) * 8)); \
            acc[ct] = __builtin_amdgcn_mfma_f32_16x16x32_bf16(a, b, acc[ct], 0, 0, 0);   \
        }                                                                          \
    }                                                                              \
    int orow0 = row0 + ((lane >> 4) * 4);                                          \
    int col = lane & 15;                                                           \
    _Pragma("unroll")                                                              \
    for (int ct = 0; ct < 8; ++ct) {                                               \
        _Pragma("unroll")                                                          \
        for (int r = 0; r < 4; ++r) {                                              \
            int row = orow0 + r;                                                   \
            if (row < n)                                                           \
                H[(size_t)row * F + ct * 16 + col] = f_to_fp8(acc[ct][r]);         \
        }                                                                          \
    }

// bf16-input variant
__global__ __launch_bounds__(256, 2)
void k_mm(const unsigned short* __restrict__ X,
          const unsigned short* __restrict__ Wp,
          unsigned char* __restrict__ H, int n) {
    const unsigned short* Abase_;
#define LOADA_BF16(kk) (*(const bf16x8*)(Abase_ + (kk) * 32))
    {
        int lane_ = threadIdx.x & 63;
        int row0_ = blockIdx.x * 64 + (threadIdx.x >> 6) * 16;
        int arow_ = row0_ + (lane_ & 15);
        if (arow_ >= n) arow_ = n - 1;
        Abase_ = X + (size_t)arow_ * F + ((lane_ >> 4) * 8);
    }
    MM_BODY(LOADA_BF16)
#undef LOADA_BF16
}

// fp32-input variant (layer 1): converts x to bf16 fragments in-register
__global__ __launch_bounds__(256, 2)
void k_mm_f32(const float* __restrict__ Xf,
              const unsigned short* __restrict__ Wp,
              unsigned char* __restrict__ H, int n) {
    const float* Abasef_;
    {
        int lane_ = threadIdx.x & 63;
        int row0_ = blockIdx.x * 64 + (threadIdx.x >> 6) * 16;
        int arow_ = row0_ + (lane_ & 15);
        if (arow_ >= n) arow_ = n - 1;
        Abasef_ = Xf + (size_t)arow_ * F + ((lane_ >> 4) * 8);
    }
#define LOADA_F32(kk) ({                                            \
        float4 a0 = *(const float4*)(Abasef_ + (kk) * 32);          \
        float4 a1 = *(const float4*)(Abasef_ + (kk) * 32 + 4);      \
        bf16x8 av;                                                  \
        av[0] = (short)f2bf(a0.x); av[1] = (short)f2bf(a0.y);       \
        av[2] = (short)f2bf(a0.z); av[3] = (short)f2bf(a0.w);       \
        av[4] = (short)f2bf(a1.x); av[5] = (short)f2bf(a1.y);       \
        av[6] = (short)f2bf(a1.z); av[7] = (short)f2bf(a1.w);       \
        av; })
    MM_BODY(LOADA_F32)
#undef LOADA_F32
}

// ---------- shared aggregate body: acc = relu(selfloop + gather + bias) ----------
#define AGG_BODY                                                                     \
    float dv = dinv[v];                                                              \
    float4 acc = fp8x4_to_f4(H8[(size_t)v * F4 + lane]);                             \
    float sl = dv * dv;                                                              \
    acc.x *= sl; acc.y *= sl; acc.z *= sl; acc.w *= sl;                              \
    int beg = rowptr[v], end = rowptr[v + 1];                                        \
    int j = beg;                                                                     \
    for (; j + 3 < end; j += 4) {                                                    \
        int s0 = col[j], s1 = col[j + 1], s2 = col[j + 2], s3 = col[j + 3];          \
        float w0 = dinv[s0] * dv, w1 = dinv[s1] * dv;                                \
        float w2 = dinv[s2] * dv, w3 = dinv[s3] * dv;                                \
        int q0 = H8[(size_t)s0 * F4 + lane];                                         \
        int q1 = H8[(size_t)s1 * F4 + lane];                                         \
        int q2 = H8[(size_t)s2 * F4 + lane];                                         \
        int q3 = H8[(size_t)s3 * F4 + lane];                                         \
        float4 h0 = fp8x4_to_f4(q0);                                                 \
        float4 h1 = fp8x4_to_f4(q1);                                                 \
        float4 h2 = fp8x4_to_f4(q2);                                                 \
        float4 h3 = fp8x4_to_f4(q3);                                                 \
        acc.x = fmaf(h0.x, w0, acc.x); acc.y = fmaf(h0.y, w0, acc.y);                \
        acc.z = fmaf(h0.z, w0, acc.z); acc.w = fmaf(h0.w, w0, acc.w);                \
        acc.x = fmaf(h1.x, w1, acc.x); acc.y = fmaf(h1.y, w1, acc.y);                \
        acc.z = fmaf(h1.z, w1, acc.z); acc.w = fmaf(h1.w, w1, acc.w);                \
        acc.x = fmaf(h2.x, w2, acc.x); acc.y = fmaf(h2.y, w2, acc.y);                \
        acc.z = fmaf(h2.z, w2, acc.z); acc.w = fmaf(h2.w, w2, acc.w);                \
        acc.x = fmaf(h3.x, w3, acc.x); acc.y = fmaf(h3.y, w3, acc.y);                \
        acc.z = fmaf(h3.z, w3, acc.z); acc.w = fmaf(h3.w, w3, acc.w);                \
    }                                                                                \
    for (; j < end; ++j) {                                                           \
        int s0 = col[j];                                                             \
        float w0 = dinv[s0] * dv;                                                    \
        float4 h0 = fp8x4_to_f4(H8[(size_t)s0 * F4 + lane]);                         \
        acc.x = fmaf(h0.x, w0, acc.x); acc.y = fmaf(h0.y, w0, acc.y);                \
        acc.z = fmaf(h0.z, w0, acc.z); acc.w = fmaf(h0.w, w0, acc.w);                \
    }                                                                                \
    float4 bb = b4[lane];                                                            \
    acc.x = fmaxf(acc.x + bb.x, 0.f);                                                \
    acc.y = fmaxf(acc.y + bb.y, 0.f);                                                \
    acc.z = fmaxf(acc.z + bb.z, 0.f);                                                \
    acc.w = fmaxf(acc.w + bb.w, 0.f);

// layers 1-2: write bf16 activations
__global__ void k_aggregate(const int* __restrict__ H8,
                            const int* __restrict__ rowptr,
                            const int* __restrict__ col,
                            const float* __restrict__ dinv,
                            const float4* __restrict__ b4,
                            ushort4* __restrict__ outq, int n) {
    int v = blockIdx.x * 8 + (threadIdx.x >> 5);
    int lane = threadIdx.x & 31;
    if (v >= n) return;
    AGG_BODY
    ushort4 o;
    o.x = f2bf(acc.x); o.y = f2bf(acc.y); o.z = f2bf(acc.z); o.w = f2bf(acc.w);
    outq[(size_t)v * F4 + lane] = o;
}

// layer 3: per-block partial sums -> coalesced scratch (NO global atomics here;
// 1.6M atomics into pooled[128] was the R9 1210µs cross-XCD line-bounce bug)
__global__ void k_aggregate_pool(const int* __restrict__ H8,
                                 const int* __restrict__ rowptr,
                                 const int* __restrict__ col,
                                 const float* __restrict__ dinv,
                                 const float4* __restrict__ b4,
                                 float4* __restrict__ part, int n) {
    int v = blockIdx.x * 8 + (threadIdx.x >> 5);
    int lane = threadIdx.x & 31;
    float4 res = {0.f, 0.f, 0.f, 0.f};
    if (v < n) {
        AGG_BODY
        res = acc;
    }
    __shared__ float4 sm[256];
    sm[threadIdx.x] = res;
    __syncthreads();
    if (threadIdx.x < 32) {
        float4 a = sm[threadIdx.x];
        for (int g = 1; g < 8; ++g) {
            float4 o = sm[g * 32 + threadIdx.x];
            a.x += o.x; a.y += o.y; a.z += o.z; a.w += o.w;
        }
        part[(size_t)blockIdx.x * 32 + threadIdx.x] = a;   // coalesced 512 B/block
    }
}

// ---------- fold block partials into pooled (128 blocks -> 16k atomics: safe) ----------
__global__ void k_reduce_pool(const float* __restrict__ part, float* pooled,
                              int nb, float inv_n) {
    int f = threadIdx.x & (F - 1);
    int half = threadIdx.x >> 7;   // 0 or 1
    float s = 0.f;
    for (int r = blockIdx.x * 2 + half; r < nb; r += gridDim.x * 2)
        s += part[(size_t)r * F + f];
    __shared__ float sm[256];
    sm[threadIdx.x] = s;
    __syncthreads();
    if (threadIdx.x < F)
        atomicAdd(&pooled[f], (sm[threadIdx.x] + sm[threadIdx.x + F]) * inv_n);
}

// ---------- final FC ----------
__global__ void k_fc(const float* __restrict__ pooled, const float* __restrict__ fcw,
                     const float* __restrict__ fcb, float* out) {
    __shared__ float sm[2 * F];
    int f = threadIdx.x;
    float p = pooled[f];
    sm[f]     = p * fcw[f * 2 + 0];
    sm[f + F] = p * fcw[f * 2 + 1];
    __syncthreads();
    for (int off = 64; off > 0; off >>= 1) {
        if (f < off) {
            sm[f]     += sm[f + off];
            sm[F + f] += sm[F + f + off];
        }
        __syncthreads();
    }
    if (f == 0) {
        out[0] = sm[0] + fcb[0];
        out[1] = sm[F] + fcb[1];
    }
}

extern "C" void kernel_launch(void* const* d_in, const int* in_sizes, int n_in,
                              void* d_out, int out_size, void* d_ws, size_t ws_size,
                              hipStream_t stream) {
    const float* x   = (const float*)d_in[0];
    const int*   ei  = (const int*)  d_in[1];
    const float* W1  = (const float*)d_in[2];
    const float* b1  = (const float*)d_in[3];
    const float* W2  = (const float*)d_in[4];
    const float* b2  = (const float*)d_in[5];
    const float* W3  = (const float*)d_in[6];
    const float* b3  = (const float*)d_in[7];
    const float* fcw = (const float*)d_in[8];
    const float* fcb = (const float*)d_in[9];
    float* out = (float*)d_out;

    const int n = in_sizes[0] / F;     // 100000
    const int e = in_sizes[1] / 2;     // 1600000
    const int* src = ei;
    const int* dst = ei + e;

    const int BT = 256;
    dim3 blk(BT);
    int gN    = (n + BT - 1) / BT;
    int gE    = (e + BT - 1) / BT;
    int gAgg  = (n + 7) / 8;           // 12500
    int gMM   = (n + 63) / 64;
    int nbScan = (n + SCAN_CHUNK - 1) / SCAN_CHUNK;   // 98

    // workspace layout (16B-aligned chunks)
    float* ws     = (float*)d_ws;
    float* dinv   = ws;                          // n
    float* pooled = dinv + n;                    // 128
    int*   rowptr = (int*)(pooled + 128);        // n+4
    int*   cnt    = rowptr + (n + 4);            // n
    int*   bsum   = cnt + n;                     // 2048
    int*   scnt   = bsum + 2048;                 // NSH*n (shard counters / bases)
    int*   col    = scnt + (size_t)NSH * n;      // e
    unsigned short* posb = (unsigned short*)(col + e);  // e ushort
    unsigned short* Wp  = posb + ((e + 7) & ~7);        // 3*16384
    float* part = (float*)(Wp + 3 * 16384);             // gAgg*128 fp32 partials
    unsigned short* Ab  = (unsigned short*)(part + (size_t)gAgg * F);  // n*F bf16
    unsigned short* Bb  = Ab + (size_t)n * F;           // n*F bf16
    unsigned char*  H8  = (unsigned char*)(Bb + (size_t)n * F);   // n*F fp8

    // ---- CSR build: XCD-sharded hist+pos, shard prefix, scan, atomic-free place ----
    hipMemsetAsync(scnt, 0, (size_t)NSH * n * sizeof(int), stream);
    hipMemsetAsync(pooled, 0, F * sizeof(float), stream);
    k_histpos<<<gE, blk, 0, stream>>>(dst, scnt, posb, e, n);
    k_offs   <<<gN, blk, 0, stream>>>(scnt, cnt, dinv, n);
    k_scan1  <<<nbScan, blk, 0, stream>>>(cnt, rowptr, bsum, n);
    k_scan2  <<<1, dim3(128), 0, stream>>>(bsum, nbScan);
    k_scan3  <<<nbScan, blk, 0, stream>>>(rowptr, bsum, n, e);
    k_place  <<<gE, blk, 0, stream>>>(src, dst, posb, rowptr, scnt, col, e, n);

    // ---- weight packing (all 3 layers, one dispatch) ----
    k_packW3<<<192, blk, 0, stream>>>(W1, W2, W3, Wp);

    // ---- 3 GCN layers: X @ W -> fp8 H -> gather(fp32 acc) -> bf16 ----
    // layer 1 (fp32 input, no cvt pass)
    k_mm_f32<<<gMM, blk, 0, stream>>>(x, Wp, H8, n);
    k_aggregate<<<gAgg, blk, 0, stream>>>((const int*)H8, rowptr, col, dinv,
                                          (const float4*)b1, (ushort4*)Ab, n);
    // layer 2
    k_mm<<<gMM, blk, 0, stream>>>(Ab, Wp + 16384, H8, n);
    k_aggregate<<<gAgg, blk, 0, stream>>>((const int*)H8, rowptr, col, dinv,
                                          (const float4*)b2, (ushort4*)Bb, n);
    // layer 3: aggregate fused with pooling via coalesced per-block partials
    k_mm<<<gMM, blk, 0, stream>>>(Bb, Wp + 2 * 16384, H8, n);
    k_aggregate_pool<<<gAgg, blk, 0, stream>>>((const int*)H8, rowptr, col, dinv,
                                               (const float4*)b3, (float4*)part, n);
    k_reduce_pool<<<128, blk, 0, stream>>>(part, pooled, gAgg, 1.0f / (float)n);

    // ---- FC ----
    k_fc<<<1, dim3(F), 0, stream>>>(pooled, fcw, fcb, out);
}

// Round 11
// 421.649 us; speedup vs baseline: 3.7483x; 1.0483x over previous
//
#include <hip/hip_runtime.h>
#include <hip/hip_bf16.h>

#define F 128          // feature dim
#define F4 32          // feature dim in 4-element quads
#define SCAN_CHUNK 1024
#define NSH 8          // counter shards (one per XCD)

typedef __attribute__((ext_vector_type(8))) short bf16x8;
typedef __attribute__((ext_vector_type(4))) float f32x4;
typedef __attribute__((ext_vector_type(2))) float f32x2;

static __device__ inline unsigned short f2bf(float f) {
    __hip_bfloat16 b = __float2bfloat16(f);
    return *(unsigned short*)&b;
}

// decode 4 packed fp8-e4m3 bytes -> 4 floats (HW cvt)
__device__ inline float4 fp8x4_to_f4(int w) {
    f32x2 lo = __builtin_amdgcn_cvt_pk_f32_fp8(w, false);
    f32x2 hi = __builtin_amdgcn_cvt_pk_f32_fp8(w, true);
    float4 f;
    f.x = lo[0]; f.y = lo[1]; f.z = hi[0]; f.w = hi[1];
    return f;
}

// encode 1 float -> fp8-e4m3 byte (HW cvt)
__device__ inline unsigned char f_to_fp8(float a) {
    int p = __builtin_amdgcn_cvt_pk_fp8_f32(a, a, 0, false);
    return (unsigned char)(p & 0xFF);
}

// physical XCD id; correctness does NOT depend on the value (shard id is
// stored per edge) — perf-only.
__device__ inline int xcc_id() {
    return (int)(__builtin_amdgcn_s_getreg((3 << 11) | 20) & (NSH - 1));
}

// ---------- fused sharded histogram + per-edge slot assignment ----------
// Device-scope atomic floor ~25G/s (R8 vs R10: sharding neutral); accepted.
__global__ void k_histpos(const int* __restrict__ dst, int* scnt,
                          unsigned short* __restrict__ posb, int e, int n) {
    int i = blockIdx.x * blockDim.x + threadIdx.x;
    if (i >= e) return;
    int sh = xcc_id();
    int pos = atomicAdd(&scnt[(size_t)sh * n + dst[i]], 1);
    posb[i] = (unsigned short)((sh << 13) | pos);
}

// ---------- fused shard-prefix + dinv + block-local exclusive scan ----------
// scnt planes -> per-node shard bases (in place) + dinv; tot -> LDS scan -> rowptr
__global__ void k_scan1(int* scnt, float* dinv, int* rowptr, int* bsum, int n) {
    __shared__ int s[SCAN_CHUNK];
    int base = blockIdx.x * SCAN_CHUNK;
    int tid = threadIdx.x;
    int tots[4];
#pragma unroll
    for (int c = 0; c < 4; ++c) {
        int v = base + tid + 256 * c;
        int tot = 0;
        if (v < n) {
#pragma unroll
            for (int sh = 0; sh < NSH; ++sh) {
                int cv = scnt[(size_t)sh * n + v];
                scnt[(size_t)sh * n + v] = tot;   // exclusive base of shard
                tot += cv;
            }
            dinv[v] = 1.0f / sqrtf((float)tot + 1.0f);
        }
        tots[c] = tot;
        s[tid + 256 * c] = tot;
    }
    __syncthreads();
    for (int off = 1; off < SCAN_CHUNK; off <<= 1) {
        int v0 = (tid       >= off) ? s[tid       - off] : 0;
        int v1 = (tid + 256 >= off) ? s[tid + 256 - off] : 0;
        int v2 = (tid + 512 >= off) ? s[tid + 512 - off] : 0;
        int v3 = (tid + 768 >= off) ? s[tid + 768 - off] : 0;
        __syncthreads();
        s[tid      ] += v0;
        s[tid + 256] += v1;
        s[tid + 512] += v2;
        s[tid + 768] += v3;
        __syncthreads();
    }
#pragma unroll
    for (int c = 0; c < 4; ++c) {
        int v = base + tid + 256 * c;
        if (v < n) rowptr[v] = s[tid + 256 * c] - tots[c];
    }
    if (tid == 0) bsum[blockIdx.x] = s[SCAN_CHUNK - 1];
}

__global__ void k_scan2(int* bsum, int nb) {
    __shared__ int s[128];
    int tid = threadIdx.x;
    int v = (tid < nb) ? bsum[tid] : 0;
    s[tid] = v;
    __syncthreads();
    for (int off = 1; off < 128; off <<= 1) {
        int u = (tid >= off) ? s[tid - off] : 0;
        __syncthreads();
        s[tid] += u;
        __syncthreads();
    }
    if (tid < nb) bsum[tid] = s[tid] - v;   // exclusive
}

__global__ void k_scan3(int* rowptr, const int* __restrict__ bsum, int n, int e) {
    int base = blockIdx.x * SCAN_CHUNK;
    int add = bsum[blockIdx.x];
    for (int t = threadIdx.x; t < SCAN_CHUNK; t += 256)
        if (base + t < n) rowptr[base + t] += add;
    if (blockIdx.x == 0 && threadIdx.x == 0) rowptr[n] = e;
}

// ---------- atomic-free CSR placement ----------
__global__ void k_place(const int* __restrict__ src, const int* __restrict__ dst,
                        const unsigned short* __restrict__ posb,
                        const int* __restrict__ rowptr, const int* __restrict__ soff,
                        int* __restrict__ col, int e, int n) {
    int i = blockIdx.x * blockDim.x + threadIdx.x;
    if (i >= e) return;
    int d = dst[i];
    int pb = (int)posb[i];
    int sh = pb >> 13;
    int pos = pb & 0x1FFF;
    col[rowptr[d] + soff[(size_t)sh * n + d] + pos] = src[i];
}

// ---------- pack all 3 W (fp32 128x128) into MFMA B-fragment order, bf16 ----------
__global__ void k_packW3(const float* __restrict__ W1, const float* __restrict__ W2,
                         const float* __restrict__ W3, unsigned short* __restrict__ Wp) {
    int gb = blockIdx.x;                        // 0..191
    const float* W = (gb < 64) ? W1 : ((gb < 128) ? W2 : W3);
    unsigned short* out = Wp + (size_t)(gb >> 6) * 16384;
    int idx = (gb & 63) * 256 + threadIdx.x;    // 0..16383
    int i    = idx & 7;
    int lane = (idx >> 3) & 63;
    int kk   = (idx >> 9) & 3;
    int ct   = idx >> 11;
    int k = kk * 32 + ((lane >> 4) * 8) + i;
    int c = ct * 16 + (lane & 15);
    out[idx] = f2bf(W[k * F + c]);
}

// ---------- MFMA matmul v2: Wp staged in LDS; 128 rows/block, 32/wave ----------
// Each B fragment (ds_read_b128) feeds 2 MFMAs (row groups A/B): B traffic /8 vs v1.
#define MM2_TAIL                                                                    \
    int orow0 = row0 + ((lane >> 4) * 4);                                           \
    int colc = lane & 15;                                                           \
    _Pragma("unroll")                                                               \
    for (int ct = 0; ct < 8; ++ct) {                                                \
        _Pragma("unroll")                                                           \
        for (int r = 0; r < 4; ++r) {                                               \
            int rowA = orow0 + r;                                                   \
            int rowB = rowA + 16;                                                   \
            if (rowA < n) H[(size_t)rowA * F + ct * 16 + colc] = f_to_fp8(accA[ct][r]); \
            if (rowB < n) H[(size_t)rowB * F + ct * 16 + colc] = f_to_fp8(accB[ct][r]); \
        }                                                                           \
    }

__global__ __launch_bounds__(256, 2)
void k_mm(const unsigned short* __restrict__ X,
          const unsigned short* __restrict__ Wp,
          unsigned char* __restrict__ H, int n) {
    __shared__ unsigned short wlds[16384];   // 32 KB
    {
        const uint4* wsrc = (const uint4*)Wp;
        uint4* wdst = (uint4*)wlds;
#pragma unroll
        for (int i = 0; i < 8; ++i)
            wdst[threadIdx.x + 256 * i] = wsrc[threadIdx.x + 256 * i];
    }
    __syncthreads();
    int wave = threadIdx.x >> 6;
    int lane = threadIdx.x & 63;
    int row0 = blockIdx.x * 128 + wave * 32;
    if (row0 >= n) return;

    int arowA = row0 + (lane & 15);
    int arowB = arowA + 16;
    if (arowA >= n) arowA = n - 1;
    if (arowB >= n) arowB = n - 1;
    const unsigned short* AbA = X + (size_t)arowA * F + ((lane >> 4) * 8);
    const unsigned short* AbB = X + (size_t)arowB * F + ((lane >> 4) * 8);

    f32x4 accA[8], accB[8];
#pragma unroll
    for (int ct = 0; ct < 8; ++ct) {
        accA[ct] = (f32x4){0.f, 0.f, 0.f, 0.f};
        accB[ct] = (f32x4){0.f, 0.f, 0.f, 0.f};
    }
#pragma unroll
    for (int kk = 0; kk < 4; ++kk) {
        bf16x8 aA = *(const bf16x8*)(AbA + kk * 32);
        bf16x8 aB = *(const bf16x8*)(AbB + kk * 32);
#pragma unroll
        for (int ct = 0; ct < 8; ++ct) {
            bf16x8 b = *(const bf16x8*)(wlds + ((size_t)(ct * 4 + kk) * 64 + lane) * 8);
            accA[ct] = __builtin_amdgcn_mfma_f32_16x16x32_bf16(aA, b, accA[ct], 0, 0, 0);
            accB[ct] = __builtin_amdgcn_mfma_f32_16x16x32_bf16(aB, b, accB[ct], 0, 0, 0);
        }
    }
    MM2_TAIL
}

// fp32-input variant (layer 1): converts x to bf16 fragments in-register
__global__ __launch_bounds__(256, 2)
void k_mm_f32(const float* __restrict__ Xf,
              const unsigned short* __restrict__ Wp,
              unsigned char* __restrict__ H, int n) {
    __shared__ unsigned short wlds[16384];
    {
        const uint4* wsrc = (const uint4*)Wp;
        uint4* wdst = (uint4*)wlds;
#pragma unroll
        for (int i = 0; i < 8; ++i)
            wdst[threadIdx.x + 256 * i] = wsrc[threadIdx.x + 256 * i];
    }
    __syncthreads();
    int wave = threadIdx.x >> 6;
    int lane = threadIdx.x & 63;
    int row0 = blockIdx.x * 128 + wave * 32;
    if (row0 >= n) return;

    int arowA = row0 + (lane & 15);
    int arowB = arowA + 16;
    if (arowA >= n) arowA = n - 1;
    if (arowB >= n) arowB = n - 1;
    const float* AbA = Xf + (size_t)arowA * F + ((lane >> 4) * 8);
    const float* AbB = Xf + (size_t)arowB * F + ((lane >> 4) * 8);

    f32x4 accA[8], accB[8];
#pragma unroll
    for (int ct = 0; ct < 8; ++ct) {
        accA[ct] = (f32x4){0.f, 0.f, 0.f, 0.f};
        accB[ct] = (f32x4){0.f, 0.f, 0.f, 0.f};
    }
#pragma unroll
    for (int kk = 0; kk < 4; ++kk) {
        float4 a0 = *(const float4*)(AbA + kk * 32);
        float4 a1 = *(const float4*)(AbA + kk * 32 + 4);
        float4 b0 = *(const float4*)(AbB + kk * 32);
        float4 b1 = *(const float4*)(AbB + kk * 32 + 4);
        bf16x8 aA, aB;
        aA[0] = (short)f2bf(a0.x); aA[1] = (short)f2bf(a0.y);
        aA[2] = (short)f2bf(a0.z); aA[3] = (short)f2bf(a0.w);
        aA[4] = (short)f2bf(a1.x); aA[5] = (short)f2bf(a1.y);
        aA[6] = (short)f2bf(a1.z); aA[7] = (short)f2bf(a1.w);
        aB[0] = (short)f2bf(b0.x); aB[1] = (short)f2bf(b0.y);
        aB[2] = (short)f2bf(b0.z); aB[3] = (short)f2bf(b0.w);
        aB[4] = (short)f2bf(b1.x); aB[5] = (short)f2bf(b1.y);
        aB[6] = (short)f2bf(b1.z); aB[7] = (short)f2bf(b1.w);
#pragma unroll
        for (int ct = 0; ct < 8; ++ct) {
            bf16x8 b = *(const bf16x8*)(wlds + ((size_t)(ct * 4 + kk) * 64 + lane) * 8);
            accA[ct] = __builtin_amdgcn_mfma_f32_16x16x32_bf16(aA, b, accA[ct], 0, 0, 0);
            accB[ct] = __builtin_amdgcn_mfma_f32_16x16x32_bf16(aB, b, accB[ct], 0, 0, 0);
        }
    }
    MM2_TAIL
}

// ---------- shared aggregate body: acc = relu(selfloop + gather + bias) ----------
// unroll x8 for 8 outstanding gathers per node (latency-bound L2/L3 random reads)
#define AGG_EDGE(s_, w_) {                                                           \
        float4 h_ = fp8x4_to_f4(H8[(size_t)(s_) * F4 + lane]);                       \
        acc.x = fmaf(h_.x, (w_), acc.x); acc.y = fmaf(h_.y, (w_), acc.y);            \
        acc.z = fmaf(h_.z, (w_), acc.z); acc.w = fmaf(h_.w, (w_), acc.w); }

#define AGG_BODY                                                                     \
    float dv = dinv[v];                                                              \
    float4 acc = fp8x4_to_f4(H8[(size_t)v * F4 + lane]);                             \
    float sl = dv * dv;                                                              \
    acc.x *= sl; acc.y *= sl; acc.z *= sl; acc.w *= sl;                              \
    int beg = rowptr[v], end = rowptr[v + 1];                                        \
    int j = beg;                                                                     \
    for (; j + 7 < end; j += 8) {                                                    \
        int s0 = col[j], s1 = col[j+1], s2 = col[j+2], s3 = col[j+3];                \
        int s4 = col[j+4], s5 = col[j+5], s6 = col[j+6], s7 = col[j+7];              \
        float w0 = dinv[s0]*dv, w1 = dinv[s1]*dv, w2 = dinv[s2]*dv, w3 = dinv[s3]*dv;\
        float w4 = dinv[s4]*dv, w5 = dinv[s5]*dv, w6 = dinv[s6]*dv, w7 = dinv[s7]*dv;\
        int q0 = H8[(size_t)s0*F4+lane], q1 = H8[(size_t)s1*F4+lane];                \
        int q2 = H8[(size_t)s2*F4+lane], q3 = H8[(size_t)s3*F4+lane];                \
        int q4 = H8[(size_t)s4*F4+lane], q5 = H8[(size_t)s5*F4+lane];                \
        int q6 = H8[(size_t)s6*F4+lane], q7 = H8[(size_t)s7*F4+lane];                \
        float4 h0 = fp8x4_to_f4(q0), h1 = fp8x4_to_f4(q1);                           \
        float4 h2 = fp8x4_to_f4(q2), h3 = fp8x4_to_f4(q3);                           \
        float4 h4 = fp8x4_to_f4(q4), h5 = fp8x4_to_f4(q5);                           \
        float4 h6 = fp8x4_to_f4(q6), h7 = fp8x4_to_f4(q7);                           \
        acc.x = fmaf(h0.x,w0,acc.x); acc.y = fmaf(h0.y,w0,acc.y);                    \
        acc.z = fmaf(h0.z,w0,acc.z); acc.w = fmaf(h0.w,w0,acc.w);                    \
        acc.x = fmaf(h1.x,w1,acc.x); acc.y = fmaf(h1.y,w1,acc.y);                    \
        acc.z = fmaf(h1.z,w1,acc.z); acc.w = fmaf(h1.w,w1,acc.w);                    \
        acc.x = fmaf(h2.x,w2,acc.x); acc.y = fmaf(h2.y,w2,acc.y);                    \
        acc.z = fmaf(h2.z,w2,acc.z); acc.w = fmaf(h2.w,w2,acc.w);                    \
        acc.x = fmaf(h3.x,w3,acc.x); acc.y = fmaf(h3.y,w3,acc.y);                    \
        acc.z = fmaf(h3.z,w3,acc.z); acc.w = fmaf(h3.w,w3,acc.w);                    \
        acc.x = fmaf(h4.x,w4,acc.x); acc.y = fmaf(h4.y,w4,acc.y);                    \
        acc.z = fmaf(h4.z,w4,acc.z); acc.w = fmaf(h4.w,w4,acc.w);                    \
        acc.x = fmaf(h5.x,w5,acc.x); acc.y = fmaf(h5.y,w5,acc.y);                    \
        acc.z = fmaf(h5.z,w5,acc.z); acc.w = fmaf(h5.w,w5,acc.w);                    \
        acc.x = fmaf(h6.x,w6,acc.x); acc.y = fmaf(h6.y,w6,acc.y);                    \
        acc.z = fmaf(h6.z,w6,acc.z); acc.w = fmaf(h6.w,w6,acc.w);                    \
        acc.x = fmaf(h7.x,w7,acc.x); acc.y = fmaf(h7.y,w7,acc.y);                    \
        acc.z = fmaf(h7.z,w7,acc.z); acc.w = fmaf(h7.w,w7,acc.w);                    \
    }                                                                                \
    for (; j + 3 < end; j += 4) {                                                    \
        int s0 = col[j], s1 = col[j+1], s2 = col[j+2], s3 = col[j+3];                \
        float w0 = dinv[s0]*dv, w1 = dinv[s1]*dv, w2 = dinv[s2]*dv, w3 = dinv[s3]*dv;\
        AGG_EDGE(s0, w0) AGG_EDGE(s1, w1) AGG_EDGE(s2, w2) AGG_EDGE(s3, w3)          \
    }                                                                                \
    for (; j < end; ++j) {                                                           \
        int s0 = col[j];                                                             \
        AGG_EDGE(s0, dinv[s0] * dv)                                                  \
    }                                                                                \
    float4 bb = b4[lane];                                                            \
    acc.x = fmaxf(acc.x + bb.x, 0.f);                                                \
    acc.y = fmaxf(acc.y + bb.y, 0.f);                                                \
    acc.z = fmaxf(acc.z + bb.z, 0.f);                                                \
    acc.w = fmaxf(acc.w + bb.w, 0.f);

// layers 1-2: write bf16 activations
__global__ void k_aggregate(const int* __restrict__ H8,
                            const int* __restrict__ rowptr,
                            const int* __restrict__ col,
                            const float* __restrict__ dinv,
                            const float4* __restrict__ b4,
                            ushort4* __restrict__ outq, int n) {
    int v = blockIdx.x * 8 + (threadIdx.x >> 5);
    int lane = threadIdx.x & 31;
    if (v >= n) return;
    AGG_BODY
    ushort4 o;
    o.x = f2bf(acc.x); o.y = f2bf(acc.y); o.z = f2bf(acc.z); o.w = f2bf(acc.w);
    outq[(size_t)v * F4 + lane] = o;
}

// layer 3: per-block partials -> coalesced scratch (NO atomics into pooled!)
__global__ void k_aggregate_pool(const int* __restrict__ H8,
                                 const int* __restrict__ rowptr,
                                 const int* __restrict__ col,
                                 const float* __restrict__ dinv,
                                 const float4* __restrict__ b4,
                                 float4* __restrict__ part, int n) {
    int v = blockIdx.x * 8 + (threadIdx.x >> 5);
    int lane = threadIdx.x & 31;
    float4 res = {0.f, 0.f, 0.f, 0.f};
    if (v < n) {
        AGG_BODY
        res = acc;
    }
    __shared__ float4 sm[256];
    sm[threadIdx.x] = res;
    __syncthreads();
    if (threadIdx.x < 32) {
        float4 a = sm[threadIdx.x];
        for (int g = 1; g < 8; ++g) {
            float4 o = sm[g * 32 + threadIdx.x];
            a.x += o.x; a.y += o.y; a.z += o.z; a.w += o.w;
        }
        part[(size_t)blockIdx.x * 32 + threadIdx.x] = a;   // coalesced 512 B/block
    }
}

// ---------- fold block partials into pooled (16k atomics total: safe) ----------
__global__ void k_reduce_pool(const float* __restrict__ part, float* pooled,
                              int nb, float inv_n) {
    int f = threadIdx.x & (F - 1);
    int half = threadIdx.x >> 7;   // 0 or 1
    float s = 0.f;
    for (int r = blockIdx.x * 2 + half; r < nb; r += gridDim.x * 2)
        s += part[(size_t)r * F + f];
    __shared__ float sm[256];
    sm[threadIdx.x] = s;
    __syncthreads();
    if (threadIdx.x < F)
        atomicAdd(&pooled[f], (sm[threadIdx.x] + sm[threadIdx.x + F]) * inv_n);
}

// ---------- final FC ----------
__global__ void k_fc(const float* __restrict__ pooled, const float* __restrict__ fcw,
                     const float* __restrict__ fcb, float* out) {
    __shared__ float sm[2 * F];
    int f = threadIdx.x;
    float p = pooled[f];
    sm[f]     = p * fcw[f * 2 + 0];
    sm[f + F] = p * fcw[f * 2 + 1];
    __syncthreads();
    for (int off = 64; off > 0; off >>= 1) {
        if (f < off) {
            sm[f]     += sm[f + off];
            sm[F + f] += sm[F + f + off];
        }
        __syncthreads();
    }
    if (f == 0) {
        out[0] = sm[0] + fcb[0];
        out[1] = sm[F] + fcb[1];
    }
}

extern "C" void kernel_launch(void* const* d_in, const int* in_sizes, int n_in,
                              void* d_out, int out_size, void* d_ws, size_t ws_size,
                              hipStream_t stream) {
    const float* x   = (const float*)d_in[0];
    const int*   ei  = (const int*)  d_in[1];
    const float* W1  = (const float*)d_in[2];
    const float* b1  = (const float*)d_in[3];
    const float* W2  = (const float*)d_in[4];
    const float* b2  = (const float*)d_in[5];
    const float* W3  = (const float*)d_in[6];
    const float* b3  = (const float*)d_in[7];
    const float* fcw = (const float*)d_in[8];
    const float* fcb = (const float*)d_in[9];
    float* out = (float*)d_out;

    const int n = in_sizes[0] / F;     // 100000
    const int e = in_sizes[1] / 2;     // 1600000
    const int* src = ei;
    const int* dst = ei + e;

    const int BT = 256;
    dim3 blk(BT);
    int gE    = (e + BT - 1) / BT;
    int gAgg  = (n + 7) / 8;           // 12500
    int gMM   = (n + 127) / 128;       // 782
    int nbScan = (n + SCAN_CHUNK - 1) / SCAN_CHUNK;   // 98

    // workspace layout (16B-aligned chunks)
    float* ws     = (float*)d_ws;
    float* dinv   = ws;                          // n
    float* pooled = dinv + n;                    // 128
    int*   rowptr = (int*)(pooled + 128);        // n+4
    int*   bsum   = rowptr + (n + 4);            // 2048
    int*   scnt   = bsum + 2048;                 // NSH*n (shard counters / bases)
    int*   col    = scnt + (size_t)NSH * n;      // e
    unsigned short* posb = (unsigned short*)(col + e);  // e ushort
    unsigned short* Wp  = posb + ((e + 7) & ~7);        // 3*16384
    float* part = (float*)(Wp + 3 * 16384);             // gAgg*128 fp32 partials
    unsigned short* Ab  = (unsigned short*)(part + (size_t)gAgg * F);  // n*F bf16
    unsigned short* Bb  = Ab + (size_t)n * F;           // n*F bf16
    unsigned char*  H8  = (unsigned char*)(Bb + (size_t)n * F);   // n*F fp8

    // ---- CSR build: sharded hist+pos, fused prefix+scan, atomic-free place ----
    hipMemsetAsync(scnt, 0, (size_t)NSH * n * sizeof(int), stream);
    hipMemsetAsync(pooled, 0, F * sizeof(float), stream);
    k_histpos<<<gE, blk, 0, stream>>>(dst, scnt, posb, e, n);
    k_scan1  <<<nbScan, blk, 0, stream>>>(scnt, dinv, rowptr, bsum, n);
    k_scan2  <<<1, dim3(128), 0, stream>>>(bsum, nbScan);
    k_scan3  <<<nbScan, blk, 0, stream>>>(rowptr, bsum, n, e);
    k_place  <<<gE, blk, 0, stream>>>(src, dst, posb, rowptr, scnt, col, e, n);

    // ---- weight packing (all 3 layers, one dispatch) ----
    k_packW3<<<192, blk, 0, stream>>>(W1, W2, W3, Wp);

    // ---- 3 GCN layers: X @ W -> fp8 H -> gather(fp32 acc) -> bf16 ----
    // layer 1 (fp32 input, no cvt pass)
    k_mm_f32<<<gMM, blk, 0, stream>>>(x, Wp, H8, n);
    k_aggregate<<<gAgg, blk, 0, stream>>>((const int*)H8, rowptr, col, dinv,
                                          (const float4*)b1, (ushort4*)Ab, n);
    // layer 2
    k_mm<<<gMM, blk, 0, stream>>>(Ab, Wp + 16384, H8, n);
    k_aggregate<<<gAgg, blk, 0, stream>>>((const int*)H8, rowptr, col, dinv,
                                          (const float4*)b2, (ushort4*)Bb, n);
    // layer 3: aggregate fused with pooling via coalesced per-block partials
    k_mm<<<gMM, blk, 0, stream>>>(Bb, Wp + 2 * 16384, H8, n);
    k_aggregate_pool<<<gAgg, blk, 0, stream>>>((const int*)H8, rowptr, col, dinv,
                                               (const float4*)b3, (float4*)part, n);
    k_reduce_pool<<<128, blk, 0, stream>>>(part, pooled, gAgg, 1.0f / (float)n);

    // ---- FC ----
    k_fc<<<1, dim3(F), 0, stream>>>(pooled, fcw, fcb, out);
}

// Round 12
// 420.056 us; speedup vs baseline: 3.7625x; 1.0038x over previous
//
#include <hip/hip_runtime.h>
#include <hip/hip_bf16.h>

#define F 128          // feature dim
#define F4 32          // feature dim in 4-element quads
#define SCAN_CHUNK 1024
#define NSH 8          // counter shards

typedef __attribute__((ext_vector_type(8))) short bf16x8;
typedef __attribute__((ext_vector_type(4))) float f32x4;
typedef __attribute__((ext_vector_type(2))) float f32x2;

static __device__ inline unsigned short f2bf(float f) {
    __hip_bfloat16 b = __float2bfloat16(f);
    return *(unsigned short*)&b;
}

// decode 4 packed fp8-e4m3 bytes -> 4 floats (HW cvt)
__device__ inline float4 fp8x4_to_f4(int w) {
    f32x2 lo = __builtin_amdgcn_cvt_pk_f32_fp8(w, false);
    f32x2 hi = __builtin_amdgcn_cvt_pk_f32_fp8(w, true);
    float4 f;
    f.x = lo[0]; f.y = lo[1]; f.z = hi[0]; f.w = hi[1];
    return f;
}

// encode 1 float -> fp8-e4m3 byte (HW cvt)
__device__ inline unsigned char f_to_fp8(float a) {
    int p = __builtin_amdgcn_cvt_pk_fp8_f32(a, a, 0, false);
    return (unsigned char)(p & 0xFF);
}

// pack 4 floats -> 4 fp8 bytes
__device__ inline int f4_to_fp8x4(float4 a) {
    int w = __builtin_amdgcn_cvt_pk_fp8_f32(a.x, a.y, 0, false);
    w = __builtin_amdgcn_cvt_pk_fp8_f32(a.z, a.w, w, true);
    return w;
}

// physical XCD id; perf-only (shard id stored per edge)
__device__ inline int xcc_id() {
    return (int)(__builtin_amdgcn_s_getreg((3 << 11) | 20) & (NSH - 1));
}

// ---------- fused sharded histogram + per-edge slot assignment ----------
// Device-scope atomic floor ~25G/s (R8 vs R10: sharding neutral); accepted.
__global__ void k_histpos(const int* __restrict__ dst, int* scnt,
                          unsigned short* __restrict__ posb, int e, int n) {
    int i = blockIdx.x * blockDim.x + threadIdx.x;
    if (i >= e) return;
    int sh = xcc_id();
    int pos = atomicAdd(&scnt[(size_t)sh * n + dst[i]], 1);
    posb[i] = (unsigned short)((sh << 13) | pos);
}

// ---------- fused shard-prefix + dinv + block-local exclusive scan ----------
__global__ void k_scan1(int* scnt, float* dinv, int* rowptr, int* bsum, int n) {
    __shared__ int s[SCAN_CHUNK];
    int base = blockIdx.x * SCAN_CHUNK;
    int tid = threadIdx.x;
    int tots[4];
#pragma unroll
    for (int c = 0; c < 4; ++c) {
        int v = base + tid + 256 * c;
        int tot = 0;
        if (v < n) {
#pragma unroll
            for (int sh = 0; sh < NSH; ++sh) {
                int cv = scnt[(size_t)sh * n + v];
                scnt[(size_t)sh * n + v] = tot;   // exclusive base of shard
                tot += cv;
            }
            dinv[v] = 1.0f / sqrtf((float)tot + 1.0f);
        }
        tots[c] = tot;
        s[tid + 256 * c] = tot;
    }
    __syncthreads();
    for (int off = 1; off < SCAN_CHUNK; off <<= 1) {
        int v0 = (tid       >= off) ? s[tid       - off] : 0;
        int v1 = (tid + 256 >= off) ? s[tid + 256 - off] : 0;
        int v2 = (tid + 512 >= off) ? s[tid + 512 - off] : 0;
        int v3 = (tid + 768 >= off) ? s[tid + 768 - off] : 0;
        __syncthreads();
        s[tid      ] += v0;
        s[tid + 256] += v1;
        s[tid + 512] += v2;
        s[tid + 768] += v3;
        __syncthreads();
    }
#pragma unroll
    for (int c = 0; c < 4; ++c) {
        int v = base + tid + 256 * c;
        if (v < n) rowptr[v] = s[tid + 256 * c] - tots[c];
    }
    if (tid == 0) bsum[blockIdx.x] = s[SCAN_CHUNK - 1];
}

__global__ void k_scan2(int* bsum, int nb) {
    __shared__ int s[128];
    int tid = threadIdx.x;
    int v = (tid < nb) ? bsum[tid] : 0;
    s[tid] = v;
    __syncthreads();
    for (int off = 1; off < 128; off <<= 1) {
        int u = (tid >= off) ? s[tid - off] : 0;
        __syncthreads();
        s[tid] += u;
        __syncthreads();
    }
    if (tid < nb) bsum[tid] = s[tid] - v;   // exclusive
}

__global__ void k_scan3(int* rowptr, const int* __restrict__ bsum, int n, int e) {
    int base = blockIdx.x * SCAN_CHUNK;
    int add = bsum[blockIdx.x];
    for (int t = threadIdx.x; t < SCAN_CHUNK; t += 256)
        if (base + t < n) rowptr[base + t] += add;
    if (blockIdx.x == 0 && threadIdx.x == 0) rowptr[n] = e;
}

// ---------- atomic-free CSR placement ----------
__global__ void k_place(const int* __restrict__ src, const int* __restrict__ dst,
                        const unsigned short* __restrict__ posb,
                        const int* __restrict__ rowptr, const int* __restrict__ soff,
                        int* __restrict__ col, int e, int n) {
    int i = blockIdx.x * blockDim.x + threadIdx.x;
    if (i >= e) return;
    int d = dst[i];
    int pb = (int)posb[i];
    int sh = pb >> 13;
    int pos = pb & 0x1FFF;
    col[rowptr[d] + soff[(size_t)sh * n + d] + pos] = src[i];
}

// ---------- pack all 3 W (fp32 128x128) into MFMA B-fragment order, bf16 ----------
__global__ void k_packW3(const float* __restrict__ W1, const float* __restrict__ W2,
                         const float* __restrict__ W3, unsigned short* __restrict__ Wp) {
    int gb = blockIdx.x;                        // 0..191
    const float* W = (gb < 64) ? W1 : ((gb < 128) ? W2 : W3);
    unsigned short* out = Wp + (size_t)(gb >> 6) * 16384;
    int idx = (gb & 63) * 256 + threadIdx.x;    // 0..16383
    int i    = idx & 7;
    int lane = (idx >> 3) & 63;
    int kk   = (idx >> 9) & 3;
    int ct   = idx >> 11;
    int k = kk * 32 + ((lane >> 4) * 8) + i;
    int c = ct * 16 + (lane & 15);
    out[idx] = f2bf(W[k * F + c]);
}

// ---------- MFMA matmul: Wp in LDS; 128 rows/block; epilogue scales by dinv ----------
// H8s[row] = fp8( (X@W)[row] * dinv[row] )  — dinv folded here so the aggregate
// needs no per-edge dinv gathers.
#define MM2_PROLOG                                                                  \
    __shared__ unsigned short wlds[16384];                                          \
    {                                                                               \
        const uint4* wsrc = (const uint4*)Wp;                                       \
        uint4* wdst = (uint4*)wlds;                                                 \
        _Pragma("unroll")                                                           \
        for (int i = 0; i < 8; ++i)                                                 \
            wdst[threadIdx.x + 256 * i] = wsrc[threadIdx.x + 256 * i];              \
    }                                                                               \
    __syncthreads();                                                                \
    int wave = threadIdx.x >> 6;                                                    \
    int lane = threadIdx.x & 63;                                                    \
    int row0 = blockIdx.x * 128 + wave * 32;                                        \
    if (row0 >= n) return;                                                          \
    int arowA = row0 + (lane & 15);                                                 \
    int arowB = arowA + 16;                                                         \
    if (arowA >= n) arowA = n - 1;                                                  \
    if (arowB >= n) arowB = n - 1;

#define MM2_TAIL                                                                    \
    int orow0 = row0 + ((lane >> 4) * 4);                                           \
    int colc = lane & 15;                                                           \
    float dvA[4], dvB[4];                                                           \
    _Pragma("unroll")                                                               \
    for (int r = 0; r < 4; ++r) {                                                   \
        int ra = orow0 + r, rb = ra + 16;                                           \
        dvA[r] = dinv[ra < n ? ra : n - 1];                                         \
        dvB[r] = dinv[rb < n ? rb : n - 1];                                         \
    }                                                                               \
    _Pragma("unroll")                                                               \
    for (int ct = 0; ct < 8; ++ct) {                                                \
        _Pragma("unroll")                                                           \
        for (int r = 0; r < 4; ++r) {                                               \
            int rowA = orow0 + r;                                                   \
            int rowB = rowA + 16;                                                   \
            if (rowA < n) H[(size_t)rowA * F + ct * 16 + colc] = f_to_fp8(accA[ct][r] * dvA[r]); \
            if (rowB < n) H[(size_t)rowB * F + ct * 16 + colc] = f_to_fp8(accB[ct][r] * dvB[r]); \
        }                                                                           \
    }

#define MM2_CORE(LOADA, LOADB)                                                      \
    f32x4 accA[8], accB[8];                                                         \
    _Pragma("unroll")                                                               \
    for (int ct = 0; ct < 8; ++ct) {                                                \
        accA[ct] = (f32x4){0.f, 0.f, 0.f, 0.f};                                     \
        accB[ct] = (f32x4){0.f, 0.f, 0.f, 0.f};                                     \
    }                                                                               \
    _Pragma("unroll")                                                               \
    for (int kk = 0; kk < 4; ++kk) {                                                \
        bf16x8 aA = LOADA(kk);                                                      \
        bf16x8 aB = LOADB(kk);                                                      \
        _Pragma("unroll")                                                           \
        for (int ct = 0; ct < 8; ++ct) {                                            \
            bf16x8 b = *(const bf16x8*)(wlds + ((size_t)(ct * 4 + kk) * 64 + lane) * 8); \
            accA[ct] = __builtin_amdgcn_mfma_f32_16x16x32_bf16(aA, b, accA[ct], 0, 0, 0); \
            accB[ct] = __builtin_amdgcn_mfma_f32_16x16x32_bf16(aB, b, accB[ct], 0, 0, 0); \
        }                                                                           \
    }

// fp32-input variant (layer 1)
__global__ __launch_bounds__(256, 2)
void k_mm_f32(const float* __restrict__ Xf,
              const unsigned short* __restrict__ Wp,
              const float* __restrict__ dinv,
              unsigned char* __restrict__ H, int n) {
    MM2_PROLOG
    const float* AbA = Xf + (size_t)arowA * F + ((lane >> 4) * 8);
    const float* AbB = Xf + (size_t)arowB * F + ((lane >> 4) * 8);
#define LA_F32(kk) ({                                               \
        float4 a0 = *(const float4*)(AbA + (kk) * 32);              \
        float4 a1 = *(const float4*)(AbA + (kk) * 32 + 4);          \
        bf16x8 av;                                                  \
        av[0] = (short)f2bf(a0.x); av[1] = (short)f2bf(a0.y);       \
        av[2] = (short)f2bf(a0.z); av[3] = (short)f2bf(a0.w);       \
        av[4] = (short)f2bf(a1.x); av[5] = (short)f2bf(a1.y);       \
        av[6] = (short)f2bf(a1.z); av[7] = (short)f2bf(a1.w);       \
        av; })
#define LB_F32(kk) ({                                               \
        float4 a0 = *(const float4*)(AbB + (kk) * 32);              \
        float4 a1 = *(const float4*)(AbB + (kk) * 32 + 4);          \
        bf16x8 av;                                                  \
        av[0] = (short)f2bf(a0.x); av[1] = (short)f2bf(a0.y);       \
        av[2] = (short)f2bf(a0.z); av[3] = (short)f2bf(a0.w);       \
        av[4] = (short)f2bf(a1.x); av[5] = (short)f2bf(a1.y);       \
        av[6] = (short)f2bf(a1.z); av[7] = (short)f2bf(a1.w);       \
        av; })
    MM2_CORE(LA_F32, LB_F32)
#undef LA_F32
#undef LB_F32
    MM2_TAIL
}

// fp8-input variant (layers 2,3): activations stored fp8, cvt to bf16 in-register
__global__ __launch_bounds__(256, 2)
void k_mm_fp8(const unsigned char* __restrict__ X8,
              const unsigned short* __restrict__ Wp,
              const float* __restrict__ dinv,
              unsigned char* __restrict__ H, int n) {
    MM2_PROLOG
    const unsigned char* AbA = X8 + (size_t)arowA * F + ((lane >> 4) * 8);
    const unsigned char* AbB = X8 + (size_t)arowB * F + ((lane >> 4) * 8);
#define LA_FP8(kk) ({                                               \
        uint2 u = *(const uint2*)(AbA + (kk) * 32);                 \
        float4 lo = fp8x4_to_f4((int)u.x);                          \
        float4 hi = fp8x4_to_f4((int)u.y);                          \
        bf16x8 av;                                                  \
        av[0] = (short)f2bf(lo.x); av[1] = (short)f2bf(lo.y);       \
        av[2] = (short)f2bf(lo.z); av[3] = (short)f2bf(lo.w);       \
        av[4] = (short)f2bf(hi.x); av[5] = (short)f2bf(hi.y);       \
        av[6] = (short)f2bf(hi.z); av[7] = (short)f2bf(hi.w);       \
        av; })
#define LB_FP8(kk) ({                                               \
        uint2 u = *(const uint2*)(AbB + (kk) * 32);                 \
        float4 lo = fp8x4_to_f4((int)u.x);                          \
        float4 hi = fp8x4_to_f4((int)u.y);                          \
        bf16x8 av;                                                  \
        av[0] = (short)f2bf(lo.x); av[1] = (short)f2bf(lo.y);       \
        av[2] = (short)f2bf(lo.z); av[3] = (short)f2bf(lo.w);       \
        av[4] = (short)f2bf(hi.x); av[5] = (short)f2bf(hi.y);       \
        av[6] = (short)f2bf(hi.z); av[7] = (short)f2bf(hi.w);       \
        av; })
    MM2_CORE(LA_FP8, LB_FP8)
#undef LA_FP8
#undef LB_FP8
    MM2_TAIL
}

// ---------- aggregate: out = relu(dv * (sum H8s[s] + H8s[v]) + b) ----------
// H8s already carries dinv[src]; per-edge work = col load + row gather + 4 adds.
#define AGG_EDGE(s_) {                                                               \
        float4 h_ = fp8x4_to_f4(H8[(size_t)(s_) * F4 + lane]);                       \
        acc.x += h_.x; acc.y += h_.y; acc.z += h_.z; acc.w += h_.w; }

#define AGG_BODY                                                                     \
    float dv = dinv[v];                                                              \
    float4 acc = fp8x4_to_f4(H8[(size_t)v * F4 + lane]);  /* selfloop term */        \
    int beg = rowptr[v], end = rowptr[v + 1];                                        \
    int j = beg;                                                                     \
    for (; j + 7 < end; j += 8) {                                                    \
        int s0 = col[j], s1 = col[j+1], s2 = col[j+2], s3 = col[j+3];                \
        int s4 = col[j+4], s5 = col[j+5], s6 = col[j+6], s7 = col[j+7];              \
        int q0 = H8[(size_t)s0*F4+lane], q1 = H8[(size_t)s1*F4+lane];                \
        int q2 = H8[(size_t)s2*F4+lane], q3 = H8[(size_t)s3*F4+lane];                \
        int q4 = H8[(size_t)s4*F4+lane], q5 = H8[(size_t)s5*F4+lane];                \
        int q6 = H8[(size_t)s6*F4+lane], q7 = H8[(size_t)s7*F4+lane];                \
        float4 h0 = fp8x4_to_f4(q0), h1 = fp8x4_to_f4(q1);                           \
        float4 h2 = fp8x4_to_f4(q2), h3 = fp8x4_to_f4(q3);                           \
        float4 h4 = fp8x4_to_f4(q4), h5 = fp8x4_to_f4(q5);                           \
        float4 h6 = fp8x4_to_f4(q6), h7 = fp8x4_to_f4(q7);                           \
        acc.x += h0.x + h1.x; acc.y += h0.y + h1.y;                                  \
        acc.z += h0.z + h1.z; acc.w += h0.w + h1.w;                                  \
        acc.x += h2.x + h3.x; acc.y += h2.y + h3.y;                                  \
        acc.z += h2.z + h3.z; acc.w += h2.w + h3.w;                                  \
        acc.x += h4.x + h5.x; acc.y += h4.y + h5.y;                                  \
        acc.z += h4.z + h5.z; acc.w += h4.w + h5.w;                                  \
        acc.x += h6.x + h7.x; acc.y += h6.y + h7.y;                                  \
        acc.z += h6.z + h7.z; acc.w += h6.w + h7.w;                                  \
    }                                                                                \
    for (; j + 3 < end; j += 4) {                                                    \
        int s0 = col[j], s1 = col[j+1], s2 = col[j+2], s3 = col[j+3];                \
        AGG_EDGE(s0) AGG_EDGE(s1) AGG_EDGE(s2) AGG_EDGE(s3)                          \
    }                                                                                \
    for (; j < end; ++j) { AGG_EDGE(col[j]) }                                        \
    float4 bb = b4[lane];                                                            \
    acc.x = fmaxf(fmaf(acc.x, dv, bb.x), 0.f);                                       \
    acc.y = fmaxf(fmaf(acc.y, dv, bb.y), 0.f);                                       \
    acc.z = fmaxf(fmaf(acc.z, dv, bb.z), 0.f);                                       \
    acc.w = fmaxf(fmaf(acc.w, dv, bb.w), 0.f);

// layers 1-2: write fp8 activations
__global__ void k_aggregate(const int* __restrict__ H8,
                            const int* __restrict__ rowptr,
                            const int* __restrict__ col,
                            const float* __restrict__ dinv,
                            const float4* __restrict__ b4,
                            int* __restrict__ out8, int n) {
    int v = blockIdx.x * 8 + (threadIdx.x >> 5);
    int lane = threadIdx.x & 31;
    if (v >= n) return;
    AGG_BODY
    out8[(size_t)v * F4 + lane] = f4_to_fp8x4(acc);
}

// layer 3: per-block partials -> coalesced scratch (NO atomics into pooled —
// 1.6M atomics into pooled[128] was the R9 1210µs cross-XCD line-bounce bug)
__global__ void k_aggregate_pool(const int* __restrict__ H8,
                                 const int* __restrict__ rowptr,
                                 const int* __restrict__ col,
                                 const float* __restrict__ dinv,
                                 const float4* __restrict__ b4,
                                 float4* __restrict__ part, int n) {
    int v = blockIdx.x * 8 + (threadIdx.x >> 5);
    int lane = threadIdx.x & 31;
    float4 res = {0.f, 0.f, 0.f, 0.f};
    if (v < n) {
        AGG_BODY
        res = acc;
    }
    __shared__ float4 sm[256];
    sm[threadIdx.x] = res;
    __syncthreads();
    if (threadIdx.x < 32) {
        float4 a = sm[threadIdx.x];
        for (int g = 1; g < 8; ++g) {
            float4 o = sm[g * 32 + threadIdx.x];
            a.x += o.x; a.y += o.y; a.z += o.z; a.w += o.w;
        }
        part[(size_t)blockIdx.x * 32 + threadIdx.x] = a;   // coalesced 512 B/block
    }
}

// ---------- fold block partials into pooled (16k atomics total: safe) ----------
__global__ void k_reduce_pool(const float* __restrict__ part, float* pooled,
                              int nb, float inv_n) {
    int f = threadIdx.x & (F - 1);
    int half = threadIdx.x >> 7;   // 0 or 1
    float s = 0.f;
    for (int r = blockIdx.x * 2 + half; r < nb; r += gridDim.x * 2)
        s += part[(size_t)r * F + f];
    __shared__ float sm[256];
    sm[threadIdx.x] = s;
    __syncthreads();
    if (threadIdx.x < F)
        atomicAdd(&pooled[f], (sm[threadIdx.x] + sm[threadIdx.x + F]) * inv_n);
}

// ---------- final FC ----------
__global__ void k_fc(const float* __restrict__ pooled, const float* __restrict__ fcw,
                     const float* __restrict__ fcb, float* out) {
    __shared__ float sm[2 * F];
    int f = threadIdx.x;
    float p = pooled[f];
    sm[f]     = p * fcw[f * 2 + 0];
    sm[f + F] = p * fcw[f * 2 + 1];
    __syncthreads();
    for (int off = 64; off > 0; off >>= 1) {
        if (f < off) {
            sm[f]     += sm[f + off];
            sm[F + f] += sm[F + f + off];
        }
        __syncthreads();
    }
    if (f == 0) {
        out[0] = sm[0] + fcb[0];
        out[1] = sm[F] + fcb[1];
    }
}

extern "C" void kernel_launch(void* const* d_in, const int* in_sizes, int n_in,
                              void* d_out, int out_size, void* d_ws, size_t ws_size,
                              hipStream_t stream) {
    const float* x   = (const float*)d_in[0];
    const int*   ei  = (const int*)  d_in[1];
    const float* W1  = (const float*)d_in[2];
    const float* b1  = (const float*)d_in[3];
    const float* W2  = (const float*)d_in[4];
    const float* b2  = (const float*)d_in[5];
    const float* W3  = (const float*)d_in[6];
    const float* b3  = (const float*)d_in[7];
    const float* fcw = (const float*)d_in[8];
    const float* fcb = (const float*)d_in[9];
    float* out = (float*)d_out;

    const int n = in_sizes[0] / F;     // 100000
    const int e = in_sizes[1] / 2;     // 1600000
    const int* src = ei;
    const int* dst = ei + e;

    const int BT = 256;
    dim3 blk(BT);
    int gE    = (e + BT - 1) / BT;
    int gAgg  = (n + 7) / 8;           // 12500
    int gMM   = (n + 127) / 128;       // 782
    int nbScan = (n + SCAN_CHUNK - 1) / SCAN_CHUNK;   // 98

    // workspace layout (16B-aligned chunks)
    float* ws     = (float*)d_ws;
    float* dinv   = ws;                          // n
    float* pooled = dinv + n;                    // 128
    int*   rowptr = (int*)(pooled + 128);        // n+4
    int*   bsum   = rowptr + (n + 4);            // 2048
    int*   scnt   = bsum + 2048;                 // NSH*n
    int*   col    = scnt + (size_t)NSH * n;      // e
    unsigned short* posb = (unsigned short*)(col + e);  // e ushort
    unsigned short* Wp  = posb + ((e + 7) & ~7);        // 3*16384
    float* part = (float*)(Wp + 3 * 16384);             // gAgg*128 fp32 partials
    unsigned char* Ab = (unsigned char*)(part + (size_t)gAgg * F);  // n*F fp8
    unsigned char* Bb = Ab + (size_t)n * F;                         // n*F fp8
    unsigned char* H8 = Bb + (size_t)n * F;                         // n*F fp8

    // ---- CSR build: sharded hist+pos, fused prefix+scan, atomic-free place ----
    hipMemsetAsync(scnt, 0, (size_t)NSH * n * sizeof(int), stream);
    hipMemsetAsync(pooled, 0, F * sizeof(float), stream);
    k_histpos<<<gE, blk, 0, stream>>>(dst, scnt, posb, e, n);
    k_scan1  <<<nbScan, blk, 0, stream>>>(scnt, dinv, rowptr, bsum, n);
    k_scan2  <<<1, dim3(128), 0, stream>>>(bsum, nbScan);
    k_scan3  <<<nbScan, blk, 0, stream>>>(rowptr, bsum, n, e);
    k_place  <<<gE, blk, 0, stream>>>(src, dst, posb, rowptr, scnt, col, e, n);

    // ---- weight packing ----
    k_packW3<<<192, blk, 0, stream>>>(W1, W2, W3, Wp);

    // ---- 3 GCN layers: X @ W (·dinv) -> fp8 H8s -> gather-sum ·dv -> fp8 act ----
    // layer 1 (fp32 input)
    k_mm_f32<<<gMM, blk, 0, stream>>>(x, Wp, dinv, H8, n);
    k_aggregate<<<gAgg, blk, 0, stream>>>((const int*)H8, rowptr, col, dinv,
                                          (const float4*)b1, (int*)Ab, n);
    // layer 2
    k_mm_fp8<<<gMM, blk, 0, stream>>>(Ab, Wp + 16384, dinv, H8, n);
    k_aggregate<<<gAgg, blk, 0, stream>>>((const int*)H8, rowptr, col, dinv,
                                          (const float4*)b2, (int*)Bb, n);
    // layer 3: aggregate fused with pooling via coalesced per-block partials
    k_mm_fp8<<<gMM, blk, 0, stream>>>(Bb, Wp + 2 * 16384, dinv, H8, n);
    k_aggregate_pool<<<gAgg, blk, 0, stream>>>((const int*)H8, rowptr, col, dinv,
                                               (const float4*)b3, (float4*)part, n);
    k_reduce_pool<<<128, blk, 0, stream>>>(part, pooled, gAgg, 1.0f / (float)n);

    // ---- FC ----
    k_fc<<<1, dim3(F), 0, stream>>>(pooled, fcw, fcb, out);
}